// Round 10
// baseline (329.194 us; speedup 1.0000x reference)
//
#include <hip/hip_runtime.h>
#include <math.h>

#define IDIM 1024
#define EDIM 256
#define NB 4
#define NT 2048
#define NROW 8192

typedef __attribute__((ext_vector_type(8))) short short8;
typedef __attribute__((ext_vector_type(4))) float f32x4;

#define MFMA16(A,B,C) __builtin_amdgcn_mfma_f32_16x16x32_bf16(A,B,C,0,0,0)
#define GLD16(gsrc, ldst) __builtin_amdgcn_global_load_lds( \
    (const __attribute__((address_space(1))) unsigned int*)(gsrc), \
    (__attribute__((address_space(3))) unsigned int*)(ldst), 16, 0, 0)

#define WAITV4() asm volatile("s_waitcnt vmcnt(4)" ::: "memory")
#define WAITV0() asm volatile("s_waitcnt vmcnt(0)" ::: "memory")
#define BAR() do { asm volatile("" ::: "memory"); __builtin_amdgcn_s_barrier(); \
                   asm volatile("" ::: "memory"); } while (0)

__device__ __forceinline__ unsigned short f2bf(float x){
    unsigned u = __builtin_bit_cast(unsigned, x);
    u += 0x7fffu + ((u >> 16) & 1u);
    return (unsigned short)(u >> 16);
}
__device__ __forceinline__ float bf2f(unsigned short h){
    unsigned u = ((unsigned)h) << 16;
    return __builtin_bit_cast(float, u);
}

// ---------------- split W -> W^T hi/lo bf16 ----------------
__global__ __launch_bounds__(256) void split_w(
    const float* __restrict__ Wq, const float* __restrict__ Wk, const float* __restrict__ Wv,
    ushort* __restrict__ Wqh, ushort* __restrict__ Wql,
    ushort* __restrict__ Wkh, ushort* __restrict__ Wkl,
    ushort* __restrict__ Wvh)
{
    int u = blockIdx.x * 256 + threadIdx.x;
    int z   = u >> 15;
    int rem = u & 32767;
    int ko  = rem >> 8;
    int e   = rem & 255;
    const float* W = (z == 0) ? Wq : (z == 1) ? Wk : Wv;
    ushort* Oh = (z == 0) ? Wqh : (z == 1) ? Wkh : Wvh;
    ushort* Ol = (z == 0) ? Wql : Wkl;
    union { ushort us[8]; uint4 v; } hi, lo;
    #pragma unroll
    for (int j = 0; j < 8; ++j) {
        float wv = W[(size_t)(ko * 8 + j) * 256 + e];
        unsigned short h = f2bf(wv);
        hi.us[j] = h;
        lo.us[j] = f2bf(wv - bf2f(h));
    }
    *(uint4*)(Oh + (size_t)e * 1024 + ko * 8) = hi.v;
    if (z < 2) *(uint4*)(Ol + (size_t)e * 1024 + ko * 8) = lo.v;
}

// ---------------- QKV projection (R8-exact: free allocator, 64x128, 2-phase) ----------------
__global__ __launch_bounds__(256) void qkv_proj(
    const float* __restrict__ X,
    const ushort* __restrict__ Whq, const ushort* __restrict__ Wlq,
    const ushort* __restrict__ Whk, const ushort* __restrict__ Wlk,
    const ushort* __restrict__ Whv,
    const float* __restrict__ bq, const float* __restrict__ bk, const float* __restrict__ bv,
    ushort* __restrict__ Qh, ushort* __restrict__ Ql,
    ushort* __restrict__ Kh, ushort* __restrict__ Kl,
    ushort* __restrict__ Vt)
{
    __shared__ ushort Ah[2][259 * 8], Al[2][259 * 8];   // unit = kq*65 + m (pad 65 vs 64)
    __shared__ ushort Bh[2][512 * 8], Bl[2][512 * 8];   // unit = kq*128 + n

    const int tid = threadIdx.x;
    const int lane = tid & 63, w = tid >> 6;
    const int ln = tid & 15, quad = (tid >> 4) & 3;
    const int z = blockIdx.z;
    const int n0 = blockIdx.x * 128, m0 = blockIdx.y * 64;
    const ushort* Wh = (z == 0) ? Whq : (z == 1) ? Whk : Whv;
    const ushort* Wl = (z == 0) ? Wlq : Wlk;

    f32x4 acc[4][2];
    #pragma unroll
    for (int mi = 0; mi < 4; ++mi)
        #pragma unroll
        for (int ni = 0; ni < 2; ++ni) acc[mi][ni] = (f32x4){0.f, 0.f, 0.f, 0.f};

    const int am = tid >> 2, ak8 = (tid & 3) * 8;
    const int unit = (tid & 3) * 65 + am;
    const float* xp = X + (size_t)(m0 + am) * IDIM + ak8;
    const ushort* bsrc0 = Wh + (size_t)(n0 + lane) * IDIM + w * 8;
    const ushort* bsrc1 = Wh + (size_t)(n0 + 64 + lane) * IDIM + w * 8;
    const ushort* blsrc0 = Wl + (size_t)(n0 + lane) * IDIM + w * 8;
    const ushort* blsrc1 = Wl + (size_t)(n0 + 64 + lane) * IDIM + w * 8;

#define QSTAGE(pb, kk) do { \
    GLD16(bsrc0 + (kk), Bh[pb] + w * 1024); \
    GLD16(bsrc1 + (kk), Bh[pb] + w * 1024 + 512); \
    if (z < 2) { GLD16(blsrc0 + (kk), Bl[pb] + w * 1024); \
                 GLD16(blsrc1 + (kk), Bl[pb] + w * 1024 + 512); } \
    float4 a0 = *(const float4*)(xp + (kk)); \
    float4 a1 = *(const float4*)(xp + (kk) + 4); \
    float xv[8] = {a0.x, a0.y, a0.z, a0.w, a1.x, a1.y, a1.z, a1.w}; \
    union { ushort us[8]; uint4 v; } hi, lo; \
    _Pragma("unroll") \
    for (int j = 0; j < 8; ++j) { \
        unsigned short hh = f2bf(xv[j]); \
        hi.us[j] = hh; \
        lo.us[j] = f2bf(xv[j] - bf2f(hh)); \
    } \
    *(uint4*)(Ah[pb] + unit * 8) = hi.v; \
    if (z < 2) *(uint4*)(Al[pb] + unit * 8) = lo.v; \
} while (0)

#define QCOMP(cb) do { \
    short8 ah[4], al4[4]; \
    _Pragma("unroll") \
    for (int mi = 0; mi < 4; ++mi) { \
        int au = quad * 65 + mi * 16 + ln; \
        ah[mi] = *(const short8*)(Ah[cb] + au * 8); \
        if (z < 2) al4[mi] = *(const short8*)(Al[cb] + au * 8); \
    } \
    __builtin_amdgcn_s_setprio(1); \
    _Pragma("unroll") \
    for (int ni = 0; ni < 2; ++ni) { \
        int bu = quad * 128 + w * 32 + ni * 16 + ln; \
        short8 bh = *(const short8*)(Bh[cb] + bu * 8); \
        if (z < 2) { \
            short8 bl = *(const short8*)(Bl[cb] + bu * 8); \
            _Pragma("unroll") \
            for (int mi = 0; mi < 4; ++mi) { \
                acc[mi][ni] = MFMA16(ah[mi], bh, acc[mi][ni]); \
                acc[mi][ni] = MFMA16(ah[mi], bl, acc[mi][ni]); \
                acc[mi][ni] = MFMA16(al4[mi], bh, acc[mi][ni]); \
            } \
        } else { \
            _Pragma("unroll") \
            for (int mi = 0; mi < 4; ++mi) \
                acc[mi][ni] = MFMA16(ah[mi], bh, acc[mi][ni]); \
        } \
    } \
    __builtin_amdgcn_s_setprio(0); \
} while (0)

    QSTAGE(0, 0);
    __syncthreads();
    #pragma unroll 1
    for (int ks2 = 0; ks2 < 16; ++ks2) {
        QSTAGE(1, ks2 * 64 + 32);
        QCOMP(0);
        __syncthreads();
        if (ks2 < 15) QSTAGE(0, ks2 * 64 + 64);
        QCOMP(1);
        __syncthreads();
    }
#undef QSTAGE
#undef QCOMP

    if (z < 2) {
        ushort* OH = (z == 0) ? Qh : Kh;
        ushort* OL = (z == 0) ? Ql : Kl;
        const float* bias = (z == 0) ? bq : bk;
        const float scale = (z == 0) ? 46.16624130844683f : 1.0f;  // 32*log2(e)
        #pragma unroll
        for (int ni = 0; ni < 2; ++ni) {
            int col = n0 + w * 32 + ni * 16 + ln;
            float bb = bias[col];
            #pragma unroll
            for (int mi = 0; mi < 4; ++mi)
                #pragma unroll
                for (int r = 0; r < 4; ++r) {
                    int row = m0 + mi * 16 + quad * 4 + r;
                    float v = (acc[mi][ni][r] + bb) * scale;
                    unsigned short hh = f2bf(v);
                    OH[(size_t)row * EDIM + col] = hh;
                    OL[(size_t)row * EDIM + col] = f2bf(v - bf2f(hh));
                }
        }
    } else {
        #pragma unroll
        for (int ni = 0; ni < 2; ++ni) {
            int col = n0 + w * 32 + ni * 16 + ln;
            float bb = bv[col];
            #pragma unroll
            for (int mi = 0; mi < 4; ++mi) {
                int rowb = m0 + mi * 16 + quad * 4;
                union { ushort us[4]; uint2 v; } pk;
                #pragma unroll
                for (int r = 0; r < 4; ++r) pk.us[r] = f2bf(acc[mi][ni][r] + bb);
                *(uint2*)(Vt + (size_t)col * NROW + rowb) = pk.v;
            }
        }
    }
}

// ---------------- attention (R4/R8 body) + FUSED last-block merge ----------------
__device__ __forceinline__ void stageK(const ushort* __restrict__ Kh,
                                       const ushort* __restrict__ Kl,
                                       ushort* buf, int kv0, int kc0, int w, int lane) {
    size_t rowoff = (size_t)(kv0 + w * 16 + (lane & 15)) * EDIM + (lane >> 4) * 8 + kc0 * 32;
    GLD16(Kh + rowoff,      buf + w * 512);
    GLD16(Kh + rowoff + 32, buf + 2048 + w * 512);
    GLD16(Kl + rowoff,      buf + 4096 + w * 512);
    GLD16(Kl + rowoff + 32, buf + 6144 + w * 512);
}

__device__ __forceinline__ void stageV(const ushort* __restrict__ Vt,
                                       ushort* buf, int kv0, int vs0, int w, int lane) {
    size_t gv = (size_t)(vs0 * 64 + w * 16 + (lane & 15)) * NROW + kv0 + (lane >> 4) * 8;
    GLD16(Vt + gv,      buf + w * 1024);
    GLD16(Vt + gv + 32, buf + w * 1024 + 512);
    GLD16(Vt + gv + (size_t)64 * NROW,      buf + 4096 + w * 1024);
    GLD16(Vt + gv + (size_t)64 * NROW + 32, buf + 4096 + w * 1024 + 512);
}

__global__ __launch_bounds__(256, 2) void attn(
    const ushort* __restrict__ Qh, const ushort* __restrict__ Ql,
    const ushort* __restrict__ Kh, const ushort* __restrict__ Kl,
    const ushort* __restrict__ Vt, ushort* __restrict__ Op, float* __restrict__ mlbuf,
    float* __restrict__ out, unsigned* __restrict__ cnt)
{
    __shared__ ushort KVbuf[3 * 8192];   // 48 KB: 3 rotating 16 KB chunk buffers
    __shared__ ushort Pall[4 * 1088];    // per-wave P slab (unit = ko*17+row)
    __shared__ unsigned lastv;

    const int tid = threadIdx.x;
    const int lane = tid & 63;
    const int ln = tid & 15, quad = (tid >> 4) & 3, w = tid >> 6;
    ushort* Pw = Pall + w * 1088;

    const int id = blockIdx.x;              // 512 = qt(32) x [b(4) x kvq(4)]
    const int cls = id & 15;
    const int b = cls >> 2, kvq = cls & 3;
    const int qt = id >> 4;
    const int qrow0w = b * NT + qt * 64 + w * 16;
    const int kvbase = b * NT + kvq * 512;

    short8 qh8[8], ql8[8];
    #pragma unroll
    for (int kc = 0; kc < 8; ++kc) {
        qh8[kc] = *(const short8*)(Qh + (size_t)(qrow0w + ln) * EDIM + kc * 32 + quad * 8);
        ql8[kc] = *(const short8*)(Ql + (size_t)(qrow0w + ln) * EDIM + kc * 32 + quad * 8);
    }

    float m_r[4], l_r[4];
    #pragma unroll
    for (int r = 0; r < 4; ++r) { m_r[r] = -3e38f; l_r[r] = 0.f; }
    f32x4 o[16];
    #pragma unroll
    for (int ni = 0; ni < 16; ++ni) o[ni] = (f32x4){0.f, 0.f, 0.f, 0.f};

    stageK(Kh, Kl, KVbuf + 0 * 8192, kvbase, 0, w, lane);
    stageK(Kh, Kl, KVbuf + 1 * 8192, kvbase, 2, w, lane);

    #pragma unroll 1
    for (int t = 0; t < 8; ++t) {
        const int kv0 = kvbase + t * 64;
        f32x4 s[4];
        #pragma unroll
        for (int ni = 0; ni < 4; ++ni) s[ni] = (f32x4){0.f, 0.f, 0.f, 0.f};

        #pragma unroll
        for (int j = 0; j < 4; ++j) {
            WAITV4();
            BAR();
            if (j < 2)      stageK(Kh, Kl, KVbuf + ((j + 2) % 3) * 8192, kv0, 2 * (j + 2), w, lane);
            else if (j == 2) stageV(Vt, KVbuf + 1 * 8192, kv0, 0, w, lane);
            else             stageV(Vt, KVbuf + 2 * 8192, kv0, 2, w, lane);

            const ushort* bufc = KVbuf + (j % 3) * 8192;
            __builtin_amdgcn_s_setprio(1);
            #pragma unroll
            for (int kk = 0; kk < 2; ++kk) {
                const int kc = j * 2 + kk;
                #pragma unroll
                for (int ni = 0; ni < 4; ++ni) {
                    short8 bh = *(const short8*)(bufc + kk * 2048 + (ni * 64 + quad * 16 + ln) * 8);
                    short8 bl = *(const short8*)(bufc + 4096 + kk * 2048 + (ni * 64 + quad * 16 + ln) * 8);
                    s[ni] = MFMA16(qh8[kc], bh, s[ni]);
                    s[ni] = MFMA16(qh8[kc], bl, s[ni]);
                    s[ni] = MFMA16(ql8[kc], bh, s[ni]);
                }
            }
            __builtin_amdgcn_s_setprio(0);
        }

        // ---- online softmax with exact rescale-skip ----
        float mt[4];
        #pragma unroll
        for (int r = 0; r < 4; ++r)
            mt[r] = fmaxf(fmaxf(s[0][r], s[1][r]), fmaxf(s[2][r], s[3][r]));
        #pragma unroll
        for (int mask = 1; mask < 16; mask <<= 1)
            #pragma unroll
            for (int r = 0; r < 4; ++r)
                mt[r] = fmaxf(mt[r], __shfl_xor(mt[r], mask));
        int need = (mt[0] > m_r[0]) || (mt[1] > m_r[1]) ||
                   (mt[2] > m_r[2]) || (mt[3] > m_r[3]);
        if (__ballot(need)) {          // alpha == 1 exactly for every skipped lane-row
            float alpha[4];
            #pragma unroll
            for (int r = 0; r < 4; ++r) {
                float mn = fmaxf(m_r[r], mt[r]);
                alpha[r] = exp2f(m_r[r] - mn);
                m_r[r] = mn;
            }
            #pragma unroll
            for (int r = 0; r < 4; ++r) l_r[r] *= alpha[r];
            #pragma unroll
            for (int ni = 0; ni < 16; ++ni)
                #pragma unroll
                for (int r = 0; r < 4; ++r) o[ni][r] *= alpha[r];
        }
        float ls[4] = {0.f, 0.f, 0.f, 0.f};
        #pragma unroll
        for (int ni = 0; ni < 4; ++ni) {
            int colb = ni * 16 + ln;
            #pragma unroll
            for (int r = 0; r < 4; ++r) {
                float p = exp2f(s[ni][r] - m_r[r]);
                ls[r] += p;
                Pw[((colb >> 3) * 17 + quad * 4 + r) * 8 + (colb & 7)] = f2bf(p);
            }
        }
        #pragma unroll
        for (int mask = 1; mask < 16; mask <<= 1)
            #pragma unroll
            for (int r = 0; r < 4; ++r)
                ls[r] += __shfl_xor(ls[r], mask);
        #pragma unroll
        for (int r = 0; r < 4; ++r) l_r[r] += ls[r];

        short8 apk0 = *(const short8*)(Pw + (quad * 17 + ln) * 8);
        short8 apk1 = *(const short8*)(Pw + ((4 + quad) * 17 + ln) * 8);

        #pragma unroll
        for (int j2 = 0; j2 < 2; ++j2) {
            if (t < 7 || j2 == 0) { WAITV4(); } else { WAITV0(); }
            BAR();
            if (t < 7) {
                if (j2 == 0) stageK(Kh, Kl, KVbuf + 0 * 8192, kv0 + 64, 0, w, lane);
                else         stageK(Kh, Kl, KVbuf + 1 * 8192, kv0 + 64, 2, w, lane);
            }
            const ushort* bufc = KVbuf + (1 + j2) * 8192;
            __builtin_amdgcn_s_setprio(1);
            #pragma unroll
            for (int vv = 0; vv < 2; ++vv) {
                const int vs = j2 * 2 + vv;
                #pragma unroll
                for (int ni = 0; ni < 4; ++ni) {
                    short8 v0 = *(const short8*)(bufc + vv * 4096 + (ni * 128 + quad * 16 + ln) * 8);
                    short8 v1 = *(const short8*)(bufc + vv * 4096 + (ni * 128 + 64 + quad * 16 + ln) * 8);
                    o[vs * 4 + ni] = MFMA16(apk0, v0, o[vs * 4 + ni]);
                    o[vs * 4 + ni] = MFMA16(apk1, v1, o[vs * 4 + ni]);
                }
            }
            __builtin_amdgcn_s_setprio(0);
        }
    }

    // ---- epilogue: wave owns rows, write bf16 partial + (m,l) ----
    const int g = b * 32 + qt;
    const int p = g * 4 + kvq;
    if (ln == 0) {
        #pragma unroll
        for (int r = 0; r < 4; ++r) {
            int row = w * 16 + quad * 4 + r;
            *(float2*)(mlbuf + ((size_t)p * 64 + row) * 2) = make_float2(m_r[r], l_r[r]);
        }
    }
    #pragma unroll
    for (int ni = 0; ni < 16; ++ni)
        #pragma unroll
        for (int r = 0; r < 4; ++r) {
            int row = w * 16 + quad * 4 + r;
            Op[(size_t)p * 16384 + row * 256 + ni * 16 + ln] = f2bf(o[ni][r]);
        }

    // ---- fused merge: last block of the 4-kvq group combines partials ----
    __threadfence();                               // release: partials visible device-wide
    if (tid == 0) lastv = atomicAdd(&cnt[g], 1u);  // device-scope atomic
    __syncthreads();
    if (lastv == 3) {
        __threadfence();                           // acquire: see other XCDs' writes
        const int pb = g * 4;
        #pragma unroll 1
        for (int rg = 0; rg < 4; ++rg) {
            const int row = rg * 16 + (tid >> 4);
            const int e0 = (tid & 15) * 16;
            float mv[4], lv[4];
            float M = -3e38f;
            #pragma unroll
            for (int w2 = 0; w2 < 4; ++w2) {
                float2 ml = *(const float2*)(mlbuf + ((size_t)(pb + w2) * 64 + row) * 2);
                mv[w2] = ml.x; lv[w2] = ml.y;
                M = fmaxf(M, ml.x);
            }
            float sc[4], denom = 0.f;
            #pragma unroll
            for (int w2 = 0; w2 < 4; ++w2) {
                sc[w2] = exp2f(mv[w2] - M);
                denom += sc[w2] * lv[w2];
            }
            float inv = 1.0f / denom;
            #pragma unroll
            for (int w2 = 0; w2 < 4; ++w2) sc[w2] *= inv;

            float acc[16] = {};
            #pragma unroll
            for (int w2 = 0; w2 < 4; ++w2) {
                const ushort* src = Op + (size_t)(pb + w2) * 16384 + row * 256 + e0;
                #pragma unroll
                for (int c = 0; c < 2; ++c) {
                    union { ushort us[8]; uint4 v; } u;
                    u.v = *(const uint4*)(src + c * 8);
                    #pragma unroll
                    for (int j = 0; j < 8; ++j)
                        acc[c * 8 + j] += sc[w2] * bf2f(u.us[j]);
                }
            }
            float* op = out + ((size_t)b * NT + qt * 64 + row) * EDIM + e0;
            #pragma unroll
            for (int gq = 0; gq < 4; ++gq)
                *(float4*)(op + gq * 4) =
                    make_float4(acc[gq*4], acc[gq*4+1], acc[gq*4+2], acc[gq*4+3]);
        }
    }
}

extern "C" void kernel_launch(void* const* d_in, const int* in_sizes, int n_in,
                              void* d_out, int out_size, void* d_ws, size_t ws_size,
                              hipStream_t stream) {
    const float* x  = (const float*)d_in[0];
    const float* Wq = (const float*)d_in[1];
    const float* bq = (const float*)d_in[2];
    const float* Wk = (const float*)d_in[3];
    const float* bk = (const float*)d_in[4];
    const float* Wv = (const float*)d_in[5];
    const float* bv = (const float*)d_in[6];
    float* out = (float*)d_out;

    const size_t NE = (size_t)NB * NT * EDIM;        // 2M elems
    ushort* Qh = (ushort*)d_ws;
    ushort* Ql = Qh + NE;
    ushort* Kh = Ql + NE;
    ushort* Kl = Kh + NE;
    ushort* Vt = Kl + NE;                            // [256][8192]
    ushort* Wqh = Vt + NE;
    ushort* Wql = Wqh + 256 * 1024;
    ushort* Wkh = Wql + 256 * 1024;
    ushort* Wkl = Wkh + 256 * 1024;
    ushort* Wvh = Wkl + 256 * 1024;
    ushort* Op  = Wvh + 256 * 1024;                  // 512 partials x 64 x 256 bf16 (16.8 MB)
    float*  mlb = (float*)(Op + (size_t)512 * 16384);// 512 x 64 x float2 (256 KB)
    unsigned* cnt = (unsigned*)(mlb + (size_t)512 * 64 * 2);  // 128 group counters
    // total ws ~= 39.6 MB + 512 B

    hipMemsetAsync(cnt, 0, 128 * sizeof(unsigned), stream);
    split_w<<<384, 256, 0, stream>>>(Wq, Wk, Wv, Wqh, Wql, Wkh, Wkl, Wvh);
    qkv_proj<<<dim3(2, 128, 3), 256, 0, stream>>>(x, Wqh, Wql, Wkh, Wkl, Wvh,
                                                  bq, bk, bv, Qh, Ql, Kh, Kl, Vt);
    attn<<<512, 256, 0, stream>>>(Qh, Ql, Kh, Kl, Vt, Op, mlb, out, cnt);
}

// Round 11
// 212.786 us; speedup vs baseline: 1.5471x; 1.5471x over previous
//
#include <hip/hip_runtime.h>
#include <math.h>

#define IDIM 1024
#define EDIM 256
#define NB 4
#define NT 2048
#define NROW 8192

typedef __attribute__((ext_vector_type(8))) short short8;
typedef __attribute__((ext_vector_type(4))) float f32x4;

#define MFMA16(A,B,C) __builtin_amdgcn_mfma_f32_16x16x32_bf16(A,B,C,0,0,0)
#define GLD16(gsrc, ldst) __builtin_amdgcn_global_load_lds( \
    (const __attribute__((address_space(1))) unsigned int*)(gsrc), \
    (__attribute__((address_space(3))) unsigned int*)(ldst), 16, 0, 0)

#define WAITV4() asm volatile("s_waitcnt vmcnt(4)" ::: "memory")
#define WAITV0() asm volatile("s_waitcnt vmcnt(0)" ::: "memory")
#define BAR() do { asm volatile("" ::: "memory"); __builtin_amdgcn_s_barrier(); \
                   asm volatile("" ::: "memory"); } while (0)

__device__ __forceinline__ unsigned short f2bf(float x){
    unsigned u = __builtin_bit_cast(unsigned, x);
    u += 0x7fffu + ((u >> 16) & 1u);
    return (unsigned short)(u >> 16);
}
__device__ __forceinline__ float bf2f(unsigned short h){
    unsigned u = ((unsigned)h) << 16;
    return __builtin_bit_cast(float, u);
}

// ---------------- QKV projection: 64x128 tile, 2-phase, W split FUSED in staging ----------------
// split_w kernel deleted: each block splits its own W f32 panel in-loop while staging
// (scalar stride-EDIM loads, lane->column coalesced -- split_w's exact access pattern).
// R3 evidence: the in-loop f32->hi/lo split hides under staging latency (pre-splitting
// X gained nothing), so this costs ~0 in-kernel while removing one dispatch + one sync
// boundary + the 5 MB W round-trip. Byte traffic unchanged (f32 == hi+lo bf16).
// NO 2nd launch_bounds arg (R5-R7: min-waves coercion spills this class).
__global__ __launch_bounds__(256) void qkv_proj(
    const float* __restrict__ X,
    const float* __restrict__ Wq, const float* __restrict__ Wk, const float* __restrict__ Wv,
    const float* __restrict__ bq, const float* __restrict__ bk, const float* __restrict__ bv,
    ushort* __restrict__ Qh, ushort* __restrict__ Ql,
    ushort* __restrict__ Kh, ushort* __restrict__ Kl,
    ushort* __restrict__ Vt)
{
    __shared__ ushort Ah[2][259 * 8], Al[2][259 * 8];   // unit = kq*65 + m (pad 65 vs 64)
    __shared__ ushort Bh[2][512 * 8], Bl[2][512 * 8];   // unit = kq*128 + n

    const int tid = threadIdx.x;
    const int ln = tid & 15, quad = (tid >> 4) & 3;
    const int w = tid >> 6;
    const int z = blockIdx.z;
    const int n0 = blockIdx.x * 128, m0 = blockIdx.y * 64;
    const float* Wf = (z == 0) ? Wq : (z == 1) ? Wk : Wv;

    f32x4 acc[4][2];
    #pragma unroll
    for (int mi = 0; mi < 4; ++mi)
        #pragma unroll
        for (int ni = 0; ni < 2; ++ni) acc[mi][ni] = (f32x4){0.f, 0.f, 0.f, 0.f};

    const int am = tid >> 2, ak8 = (tid & 3) * 8;
    const int unit = (tid & 3) * 65 + am;
    const float* xp = X + (size_t)(m0 + am) * IDIM + ak8;
    // W staging: thread handles column n0+bn for kq = bkq2 and bkq2+2 (8 k's each)
    const int bn = tid & 127, bkq2 = tid >> 7;
    const float* wp0 = Wf + (size_t)(bkq2 * 8) * EDIM + n0 + bn;
    const float* wp1 = Wf + (size_t)((bkq2 + 2) * 8) * EDIM + n0 + bn;

#define WSPLIT(pb, wp, kqv, kk) do { \
    union { ushort us[8]; uint4 v; } hi, lo; \
    _Pragma("unroll") \
    for (int j = 0; j < 8; ++j) { \
        float wv = (wp)[(size_t)((kk) + j) * EDIM]; \
        unsigned short hh = f2bf(wv); \
        hi.us[j] = hh; \
        lo.us[j] = f2bf(wv - bf2f(hh)); \
    } \
    *(uint4*)(Bh[pb] + ((kqv) * 128 + bn) * 8) = hi.v; \
    if (z < 2) *(uint4*)(Bl[pb] + ((kqv) * 128 + bn) * 8) = lo.v; \
} while (0)

#define QSTAGE(pb, kk) do { \
    WSPLIT(pb, wp0, bkq2, kk); \
    WSPLIT(pb, wp1, bkq2 + 2, kk); \
    float4 a0 = *(const float4*)(xp + (kk)); \
    float4 a1 = *(const float4*)(xp + (kk) + 4); \
    float xv[8] = {a0.x, a0.y, a0.z, a0.w, a1.x, a1.y, a1.z, a1.w}; \
    union { ushort us[8]; uint4 v; } hi, lo; \
    _Pragma("unroll") \
    for (int j = 0; j < 8; ++j) { \
        unsigned short hh = f2bf(xv[j]); \
        hi.us[j] = hh; \
        lo.us[j] = f2bf(xv[j] - bf2f(hh)); \
    } \
    *(uint4*)(Ah[pb] + unit * 8) = hi.v; \
    if (z < 2) *(uint4*)(Al[pb] + unit * 8) = lo.v; \
} while (0)

#define QCOMP(cb) do { \
    short8 ah[4], al4[4]; \
    _Pragma("unroll") \
    for (int mi = 0; mi < 4; ++mi) { \
        int au = quad * 65 + mi * 16 + ln; \
        ah[mi] = *(const short8*)(Ah[cb] + au * 8); \
        if (z < 2) al4[mi] = *(const short8*)(Al[cb] + au * 8); \
    } \
    __builtin_amdgcn_s_setprio(1); \
    _Pragma("unroll") \
    for (int ni = 0; ni < 2; ++ni) { \
        int bu = quad * 128 + w * 32 + ni * 16 + ln; \
        short8 bh = *(const short8*)(Bh[cb] + bu * 8); \
        if (z < 2) { \
            short8 bl = *(const short8*)(Bl[cb] + bu * 8); \
            _Pragma("unroll") \
            for (int mi = 0; mi < 4; ++mi) { \
                acc[mi][ni] = MFMA16(ah[mi], bh, acc[mi][ni]); \
                acc[mi][ni] = MFMA16(ah[mi], bl, acc[mi][ni]); \
                acc[mi][ni] = MFMA16(al4[mi], bh, acc[mi][ni]); \
            } \
        } else { \
            _Pragma("unroll") \
            for (int mi = 0; mi < 4; ++mi) \
                acc[mi][ni] = MFMA16(ah[mi], bh, acc[mi][ni]); \
        } \
    } \
    __builtin_amdgcn_s_setprio(0); \
} while (0)

    QSTAGE(0, 0);
    __syncthreads();
    #pragma unroll 1
    for (int ks2 = 0; ks2 < 16; ++ks2) {
        QSTAGE(1, ks2 * 64 + 32);
        QCOMP(0);
        __syncthreads();
        if (ks2 < 15) QSTAGE(0, ks2 * 64 + 64);
        QCOMP(1);
        __syncthreads();
    }
#undef QSTAGE
#undef WSPLIT
#undef QCOMP

    if (z < 2) {
        ushort* OH = (z == 0) ? Qh : Kh;
        ushort* OL = (z == 0) ? Ql : Kl;
        const float* bias = (z == 0) ? bq : bk;
        const float scale = (z == 0) ? 46.16624130844683f : 1.0f;  // 32*log2(e)
        #pragma unroll
        for (int ni = 0; ni < 2; ++ni) {
            int col = n0 + w * 32 + ni * 16 + ln;
            float bb = bias[col];
            #pragma unroll
            for (int mi = 0; mi < 4; ++mi)
                #pragma unroll
                for (int r = 0; r < 4; ++r) {
                    int row = m0 + mi * 16 + quad * 4 + r;
                    float v = (acc[mi][ni][r] + bb) * scale;
                    unsigned short hh = f2bf(v);
                    OH[(size_t)row * EDIM + col] = hh;
                    OL[(size_t)row * EDIM + col] = f2bf(v - bf2f(hh));
                }
        }
    } else {
        #pragma unroll
        for (int ni = 0; ni < 2; ++ni) {
            int col = n0 + w * 32 + ni * 16 + ln;
            float bb = bv[col];
            #pragma unroll
            for (int mi = 0; mi < 4; ++mi) {
                int rowb = m0 + mi * 16 + quad * 4;
                union { ushort us[4]; uint2 v; } pk;
                #pragma unroll
                for (int r = 0; r < 4; ++r) pk.us[r] = f2bf(acc[mi][ni][r] + bb);
                *(uint2*)(Vt + (size_t)col * NROW + rowb) = pk.v;
            }
        }
    }
}

// ---------------- attention (R4/R8-exact: 68us verified; do not touch) ----------------
__device__ __forceinline__ void stageK(const ushort* __restrict__ Kh,
                                       const ushort* __restrict__ Kl,
                                       ushort* buf, int kv0, int kc0, int w, int lane) {
    size_t rowoff = (size_t)(kv0 + w * 16 + (lane & 15)) * EDIM + (lane >> 4) * 8 + kc0 * 32;
    GLD16(Kh + rowoff,      buf + w * 512);
    GLD16(Kh + rowoff + 32, buf + 2048 + w * 512);
    GLD16(Kl + rowoff,      buf + 4096 + w * 512);
    GLD16(Kl + rowoff + 32, buf + 6144 + w * 512);
}

__device__ __forceinline__ void stageV(const ushort* __restrict__ Vt,
                                       ushort* buf, int kv0, int vs0, int w, int lane) {
    size_t gv = (size_t)(vs0 * 64 + w * 16 + (lane & 15)) * NROW + kv0 + (lane >> 4) * 8;
    GLD16(Vt + gv,      buf + w * 1024);
    GLD16(Vt + gv + 32, buf + w * 1024 + 512);
    GLD16(Vt + gv + (size_t)64 * NROW,      buf + 4096 + w * 1024);
    GLD16(Vt + gv + (size_t)64 * NROW + 32, buf + 4096 + w * 1024 + 512);
}

__global__ __launch_bounds__(256, 2) void attn(
    const ushort* __restrict__ Qh, const ushort* __restrict__ Ql,
    const ushort* __restrict__ Kh, const ushort* __restrict__ Kl,
    const ushort* __restrict__ Vt, ushort* __restrict__ Op, float* __restrict__ mlbuf)
{
    __shared__ ushort KVbuf[3 * 8192];   // 48 KB: 3 rotating 16 KB chunk buffers
    __shared__ ushort Pall[4 * 1088];    // per-wave P slab (unit = ko*17+row)

    const int tid = threadIdx.x;
    const int lane = tid & 63;
    const int ln = tid & 15, quad = (tid >> 4) & 3, w = tid >> 6;
    ushort* Pw = Pall + w * 1088;

    const int id = blockIdx.x;              // 512 = qt(32) x [b(4) x kvq(4)]
    const int cls = id & 15;
    const int b = cls >> 2, kvq = cls & 3;
    const int qt = id >> 4;
    const int qrow0w = b * NT + qt * 64 + w * 16;
    const int kvbase = b * NT + kvq * 512;

    short8 qh8[8], ql8[8];
    #pragma unroll
    for (int kc = 0; kc < 8; ++kc) {
        qh8[kc] = *(const short8*)(Qh + (size_t)(qrow0w + ln) * EDIM + kc * 32 + quad * 8);
        ql8[kc] = *(const short8*)(Ql + (size_t)(qrow0w + ln) * EDIM + kc * 32 + quad * 8);
    }

    float m_r[4], l_r[4];
    #pragma unroll
    for (int r = 0; r < 4; ++r) { m_r[r] = -3e38f; l_r[r] = 0.f; }
    f32x4 o[16];
    #pragma unroll
    for (int ni = 0; ni < 16; ++ni) o[ni] = (f32x4){0.f, 0.f, 0.f, 0.f};

    stageK(Kh, Kl, KVbuf + 0 * 8192, kvbase, 0, w, lane);
    stageK(Kh, Kl, KVbuf + 1 * 8192, kvbase, 2, w, lane);

    #pragma unroll 1
    for (int t = 0; t < 8; ++t) {
        const int kv0 = kvbase + t * 64;
        f32x4 s[4];
        #pragma unroll
        for (int ni = 0; ni < 4; ++ni) s[ni] = (f32x4){0.f, 0.f, 0.f, 0.f};

        #pragma unroll
        for (int j = 0; j < 4; ++j) {
            WAITV4();
            BAR();
            if (j < 2)      stageK(Kh, Kl, KVbuf + ((j + 2) % 3) * 8192, kv0, 2 * (j + 2), w, lane);
            else if (j == 2) stageV(Vt, KVbuf + 1 * 8192, kv0, 0, w, lane);
            else             stageV(Vt, KVbuf + 2 * 8192, kv0, 2, w, lane);

            const ushort* bufc = KVbuf + (j % 3) * 8192;
            __builtin_amdgcn_s_setprio(1);
            #pragma unroll
            for (int kk = 0; kk < 2; ++kk) {
                const int kc = j * 2 + kk;
                #pragma unroll
                for (int ni = 0; ni < 4; ++ni) {
                    short8 bh = *(const short8*)(bufc + kk * 2048 + (ni * 64 + quad * 16 + ln) * 8);
                    short8 bl = *(const short8*)(bufc + 4096 + kk * 2048 + (ni * 64 + quad * 16 + ln) * 8);
                    s[ni] = MFMA16(qh8[kc], bh, s[ni]);
                    s[ni] = MFMA16(qh8[kc], bl, s[ni]);
                    s[ni] = MFMA16(ql8[kc], bh, s[ni]);
                }
            }
            __builtin_amdgcn_s_setprio(0);
        }

        // ---- online softmax with exact rescale-skip ----
        float mt[4];
        #pragma unroll
        for (int r = 0; r < 4; ++r)
            mt[r] = fmaxf(fmaxf(s[0][r], s[1][r]), fmaxf(s[2][r], s[3][r]));
        #pragma unroll
        for (int mask = 1; mask < 16; mask <<= 1)
            #pragma unroll
            for (int r = 0; r < 4; ++r)
                mt[r] = fmaxf(mt[r], __shfl_xor(mt[r], mask));
        int need = (mt[0] > m_r[0]) || (mt[1] > m_r[1]) ||
                   (mt[2] > m_r[2]) || (mt[3] > m_r[3]);
        if (__ballot(need)) {          // alpha == 1 exactly for every skipped lane-row
            float alpha[4];
            #pragma unroll
            for (int r = 0; r < 4; ++r) {
                float mn = fmaxf(m_r[r], mt[r]);
                alpha[r] = exp2f(m_r[r] - mn);
                m_r[r] = mn;
            }
            #pragma unroll
            for (int r = 0; r < 4; ++r) l_r[r] *= alpha[r];
            #pragma unroll
            for (int ni = 0; ni < 16; ++ni)
                #pragma unroll
                for (int r = 0; r < 4; ++r) o[ni][r] *= alpha[r];
        }
        float ls[4] = {0.f, 0.f, 0.f, 0.f};
        #pragma unroll
        for (int ni = 0; ni < 4; ++ni) {
            int colb = ni * 16 + ln;
            #pragma unroll
            for (int r = 0; r < 4; ++r) {
                float p = exp2f(s[ni][r] - m_r[r]);
                ls[r] += p;
                Pw[((colb >> 3) * 17 + quad * 4 + r) * 8 + (colb & 7)] = f2bf(p);
            }
        }
        #pragma unroll
        for (int mask = 1; mask < 16; mask <<= 1)
            #pragma unroll
            for (int r = 0; r < 4; ++r)
                ls[r] += __shfl_xor(ls[r], mask);
        #pragma unroll
        for (int r = 0; r < 4; ++r) l_r[r] += ls[r];

        short8 apk0 = *(const short8*)(Pw + (quad * 17 + ln) * 8);
        short8 apk1 = *(const short8*)(Pw + ((4 + quad) * 17 + ln) * 8);

        #pragma unroll
        for (int j2 = 0; j2 < 2; ++j2) {
            if (t < 7 || j2 == 0) { WAITV4(); } else { WAITV0(); }
            BAR();
            if (t < 7) {
                if (j2 == 0) stageK(Kh, Kl, KVbuf + 0 * 8192, kv0 + 64, 0, w, lane);
                else         stageK(Kh, Kl, KVbuf + 1 * 8192, kv0 + 64, 2, w, lane);
            }
            const ushort* bufc = KVbuf + (1 + j2) * 8192;
            __builtin_amdgcn_s_setprio(1);
            #pragma unroll
            for (int vv = 0; vv < 2; ++vv) {
                const int vs = j2 * 2 + vv;
                #pragma unroll
                for (int ni = 0; ni < 4; ++ni) {
                    short8 v0 = *(const short8*)(bufc + vv * 4096 + (ni * 128 + quad * 16 + ln) * 8);
                    short8 v1 = *(const short8*)(bufc + vv * 4096 + (ni * 128 + 64 + quad * 16 + ln) * 8);
                    o[vs * 4 + ni] = MFMA16(apk0, v0, o[vs * 4 + ni]);
                    o[vs * 4 + ni] = MFMA16(apk1, v1, o[vs * 4 + ni]);
                }
            }
            __builtin_amdgcn_s_setprio(0);
        }
    }

    // ---- epilogue: wave owns rows, write bf16 partial + (m,l) ----
    const int p = (b * 32 + qt) * 4 + kvq;
    if (ln == 0) {
        #pragma unroll
        for (int r = 0; r < 4; ++r) {
            int row = w * 16 + quad * 4 + r;
            *(float2*)(mlbuf + ((size_t)p * 64 + row) * 2) = make_float2(m_r[r], l_r[r]);
        }
    }
    #pragma unroll
    for (int ni = 0; ni < 16; ++ni)
        #pragma unroll
        for (int r = 0; r < 4; ++r) {
            int row = w * 16 + quad * 4 + r;
            Op[(size_t)p * 16384 + row * 256 + ni * 16 + ln] = f2bf(o[ni][r]);
        }
}

// ---------------- final merge of 4 kv-quarter partials ----------------
__global__ __launch_bounds__(256) void attn_merge(
    const ushort* __restrict__ Op, const float* __restrict__ mlbuf, float* __restrict__ out)
{
    const int bid = blockIdx.x, t = threadIdx.x;   // 512 blocks: b(4) x qt(32) x rg(4)
    const int b = bid >> 7, qt = (bid >> 2) & 31, rg = bid & 3;
    const int row = rg * 16 + (t >> 4);
    const int e0 = (t & 15) * 16;
    const int pb = (b * 32 + qt) * 4;
    float mv[4], lv[4];
    float M = -3e38f;
    #pragma unroll
    for (int w2 = 0; w2 < 4; ++w2) {
        float2 ml = *(const float2*)(mlbuf + ((size_t)(pb + w2) * 64 + row) * 2);
        mv[w2] = ml.x; lv[w2] = ml.y;
        M = fmaxf(M, ml.x);
    }
    float sc[4], denom = 0.f;
    #pragma unroll
    for (int w2 = 0; w2 < 4; ++w2) {
        sc[w2] = exp2f(mv[w2] - M);
        denom += sc[w2] * lv[w2];
    }
    float inv = 1.0f / denom;
    #pragma unroll
    for (int w2 = 0; w2 < 4; ++w2) sc[w2] *= inv;

    float acc[16] = {};
    #pragma unroll
    for (int w2 = 0; w2 < 4; ++w2) {
        const ushort* src = Op + (size_t)(pb + w2) * 16384 + row * 256 + e0;
        #pragma unroll
        for (int c = 0; c < 2; ++c) {
            union { ushort us[8]; uint4 v; } u;
            u.v = *(const uint4*)(src + c * 8);
            #pragma unroll
            for (int j = 0; j < 8; ++j)
                acc[c * 8 + j] += sc[w2] * bf2f(u.us[j]);
        }
    }
    float* op = out + ((size_t)b * NT + qt * 64 + row) * EDIM + e0;
    #pragma unroll
    for (int g = 0; g < 4; ++g)
        *(float4*)(op + g * 4) = make_float4(acc[g*4], acc[g*4+1], acc[g*4+2], acc[g*4+3]);
}

extern "C" void kernel_launch(void* const* d_in, const int* in_sizes, int n_in,
                              void* d_out, int out_size, void* d_ws, size_t ws_size,
                              hipStream_t stream) {
    const float* x  = (const float*)d_in[0];
    const float* Wq = (const float*)d_in[1];
    const float* bq = (const float*)d_in[2];
    const float* Wk = (const float*)d_in[3];
    const float* bk = (const float*)d_in[4];
    const float* Wv = (const float*)d_in[5];
    const float* bv = (const float*)d_in[6];
    float* out = (float*)d_out;

    const size_t NE = (size_t)NB * NT * EDIM;        // 2M elems
    ushort* Qh = (ushort*)d_ws;
    ushort* Ql = Qh + NE;
    ushort* Kh = Ql + NE;
    ushort* Kl = Kh + NE;
    ushort* Vt = Kl + NE;                            // [256][8192]
    ushort* Op  = Vt + NE;                           // 512 partials x 64 x 256 bf16 (16.8 MB)
    float*  mlb = (float*)(Op + (size_t)512 * 16384);// 512 x 64 x float2 (256 KB)
    // total ws ~= 37 MB

    qkv_proj<<<dim3(2, 128, 3), 256, 0, stream>>>(x, Wq, Wk, Wv,
                                                  bq, bk, bv, Qh, Ql, Kh, Kl, Vt);
    attn<<<512, 256, 0, stream>>>(Qh, Ql, Kh, Kl, Vt, Op, mlb);
    attn_merge<<<512, 256, 0, stream>>>(Op, mlb, out);
}

// Round 12
// 202.475 us; speedup vs baseline: 1.6258x; 1.0509x over previous
//
#include <hip/hip_runtime.h>
#include <math.h>

#define IDIM 1024
#define EDIM 256
#define NB 4
#define NT 2048
#define NROW 8192

typedef __attribute__((ext_vector_type(8))) short short8;
typedef __attribute__((ext_vector_type(4))) float f32x4;

#define MFMA16(A,B,C) __builtin_amdgcn_mfma_f32_16x16x32_bf16(A,B,C,0,0,0)
#define GLD16(gsrc, ldst) __builtin_amdgcn_global_load_lds( \
    (const __attribute__((address_space(1))) unsigned int*)(gsrc), \
    (__attribute__((address_space(3))) unsigned int*)(ldst), 16, 0, 0)

#define WAITV4() asm volatile("s_waitcnt vmcnt(4)" ::: "memory")
#define WAITV0() asm volatile("s_waitcnt vmcnt(0)" ::: "memory")
#define BAR() do { asm volatile("" ::: "memory"); __builtin_amdgcn_s_barrier(); \
                   asm volatile("" ::: "memory"); } while (0)

__device__ __forceinline__ unsigned short f2bf(float x){
    unsigned u = __builtin_bit_cast(unsigned, x);
    u += 0x7fffu + ((u >> 16) & 1u);
    return (unsigned short)(u >> 16);
}
__device__ __forceinline__ float bf2f(unsigned short h){
    unsigned u = ((unsigned)h) << 16;
    return __builtin_bit_cast(float, u);
}

// ---------------- split W -> W^T hi/lo bf16 ----------------
__global__ __launch_bounds__(256) void split_w(
    const float* __restrict__ Wq, const float* __restrict__ Wk, const float* __restrict__ Wv,
    ushort* __restrict__ Wqh, ushort* __restrict__ Wql,
    ushort* __restrict__ Wkh, ushort* __restrict__ Wkl,
    ushort* __restrict__ Wvh)
{
    int u = blockIdx.x * 256 + threadIdx.x;
    int z   = u >> 15;
    int rem = u & 32767;
    int ko  = rem >> 8;
    int e   = rem & 255;
    const float* W = (z == 0) ? Wq : (z == 1) ? Wk : Wv;
    ushort* Oh = (z == 0) ? Wqh : (z == 1) ? Wkh : Wvh;
    ushort* Ol = (z == 0) ? Wql : Wkl;
    union { ushort us[8]; uint4 v; } hi, lo;
    #pragma unroll
    for (int j = 0; j < 8; ++j) {
        float wv = W[(size_t)(ko * 8 + j) * 256 + e];
        unsigned short h = f2bf(wv);
        hi.us[j] = h;
        lo.us[j] = f2bf(wv - bf2f(h));
    }
    *(uint4*)(Oh + (size_t)e * 1024 + ko * 8) = hi.v;
    if (z < 2) *(uint4*)(Ol + (size_t)e * 1024 + ko * 8) = lo.v;
}

// ---------------- QKV projection (R8-exact: free allocator, 64x128, 2-phase) ----------------
__global__ __launch_bounds__(256) void qkv_proj(
    const float* __restrict__ X,
    const ushort* __restrict__ Whq, const ushort* __restrict__ Wlq,
    const ushort* __restrict__ Whk, const ushort* __restrict__ Wlk,
    const ushort* __restrict__ Whv,
    const float* __restrict__ bq, const float* __restrict__ bk, const float* __restrict__ bv,
    ushort* __restrict__ Qh, ushort* __restrict__ Ql,
    ushort* __restrict__ Kh, ushort* __restrict__ Kl,
    ushort* __restrict__ Vt)
{
    __shared__ ushort Ah[2][259 * 8], Al[2][259 * 8];   // unit = kq*65 + m (pad 65 vs 64)
    __shared__ ushort Bh[2][512 * 8], Bl[2][512 * 8];   // unit = kq*128 + n

    const int tid = threadIdx.x;
    const int lane = tid & 63, w = tid >> 6;
    const int ln = tid & 15, quad = (tid >> 4) & 3;
    const int z = blockIdx.z;
    const int n0 = blockIdx.x * 128, m0 = blockIdx.y * 64;
    const ushort* Wh = (z == 0) ? Whq : (z == 1) ? Whk : Whv;
    const ushort* Wl = (z == 0) ? Wlq : Wlk;

    f32x4 acc[4][2];
    #pragma unroll
    for (int mi = 0; mi < 4; ++mi)
        #pragma unroll
        for (int ni = 0; ni < 2; ++ni) acc[mi][ni] = (f32x4){0.f, 0.f, 0.f, 0.f};

    const int am = tid >> 2, ak8 = (tid & 3) * 8;
    const int unit = (tid & 3) * 65 + am;
    const float* xp = X + (size_t)(m0 + am) * IDIM + ak8;
    const ushort* bsrc0 = Wh + (size_t)(n0 + lane) * IDIM + w * 8;
    const ushort* bsrc1 = Wh + (size_t)(n0 + 64 + lane) * IDIM + w * 8;
    const ushort* blsrc0 = Wl + (size_t)(n0 + lane) * IDIM + w * 8;
    const ushort* blsrc1 = Wl + (size_t)(n0 + 64 + lane) * IDIM + w * 8;

#define QSTAGE(pb, kk) do { \
    GLD16(bsrc0 + (kk), Bh[pb] + w * 1024); \
    GLD16(bsrc1 + (kk), Bh[pb] + w * 1024 + 512); \
    if (z < 2) { GLD16(blsrc0 + (kk), Bl[pb] + w * 1024); \
                 GLD16(blsrc1 + (kk), Bl[pb] + w * 1024 + 512); } \
    float4 a0 = *(const float4*)(xp + (kk)); \
    float4 a1 = *(const float4*)(xp + (kk) + 4); \
    float xv[8] = {a0.x, a0.y, a0.z, a0.w, a1.x, a1.y, a1.z, a1.w}; \
    union { ushort us[8]; uint4 v; } hi, lo; \
    _Pragma("unroll") \
    for (int j = 0; j < 8; ++j) { \
        unsigned short hh = f2bf(xv[j]); \
        hi.us[j] = hh; \
        lo.us[j] = f2bf(xv[j] - bf2f(hh)); \
    } \
    *(uint4*)(Ah[pb] + unit * 8) = hi.v; \
    if (z < 2) *(uint4*)(Al[pb] + unit * 8) = lo.v; \
} while (0)

#define QCOMP(cb) do { \
    short8 ah[4], al4[4]; \
    _Pragma("unroll") \
    for (int mi = 0; mi < 4; ++mi) { \
        int au = quad * 65 + mi * 16 + ln; \
        ah[mi] = *(const short8*)(Ah[cb] + au * 8); \
        if (z < 2) al4[mi] = *(const short8*)(Al[cb] + au * 8); \
    } \
    __builtin_amdgcn_s_setprio(1); \
    _Pragma("unroll") \
    for (int ni = 0; ni < 2; ++ni) { \
        int bu = quad * 128 + w * 32 + ni * 16 + ln; \
        short8 bh = *(const short8*)(Bh[cb] + bu * 8); \
        if (z < 2) { \
            short8 bl = *(const short8*)(Bl[cb] + bu * 8); \
            _Pragma("unroll") \
            for (int mi = 0; mi < 4; ++mi) { \
                acc[mi][ni] = MFMA16(ah[mi], bh, acc[mi][ni]); \
                acc[mi][ni] = MFMA16(ah[mi], bl, acc[mi][ni]); \
                acc[mi][ni] = MFMA16(al4[mi], bh, acc[mi][ni]); \
            } \
        } else { \
            _Pragma("unroll") \
            for (int mi = 0; mi < 4; ++mi) \
                acc[mi][ni] = MFMA16(ah[mi], bh, acc[mi][ni]); \
        } \
    } \
    __builtin_amdgcn_s_setprio(0); \
} while (0)

    QSTAGE(0, 0);
    __syncthreads();
    #pragma unroll 1
    for (int ks2 = 0; ks2 < 16; ++ks2) {
        QSTAGE(1, ks2 * 64 + 32);
        QCOMP(0);
        __syncthreads();
        if (ks2 < 15) QSTAGE(0, ks2 * 64 + 64);
        QCOMP(1);
        __syncthreads();
    }
#undef QSTAGE
#undef QCOMP

    if (z < 2) {
        ushort* OH = (z == 0) ? Qh : Kh;
        ushort* OL = (z == 0) ? Ql : Kl;
        const float* bias = (z == 0) ? bq : bk;
        const float scale = (z == 0) ? 46.16624130844683f : 1.0f;  // 32*log2(e)
        #pragma unroll
        for (int ni = 0; ni < 2; ++ni) {
            int col = n0 + w * 32 + ni * 16 + ln;
            float bb = bias[col];
            #pragma unroll
            for (int mi = 0; mi < 4; ++mi)
                #pragma unroll
                for (int r = 0; r < 4; ++r) {
                    int row = m0 + mi * 16 + quad * 4 + r;
                    float v = (acc[mi][ni][r] + bb) * scale;
                    unsigned short hh = f2bf(v);
                    OH[(size_t)row * EDIM + col] = hh;
                    OL[(size_t)row * EDIM + col] = f2bf(v - bf2f(hh));
                }
        }
    } else {
        #pragma unroll
        for (int ni = 0; ni < 2; ++ni) {
            int col = n0 + w * 32 + ni * 16 + ln;
            float bb = bv[col];
            #pragma unroll
            for (int mi = 0; mi < 4; ++mi) {
                int rowb = m0 + mi * 16 + quad * 4;
                union { ushort us[4]; uint2 v; } pk;
                #pragma unroll
                for (int r = 0; r < 4; ++r) pk.us[r] = f2bf(acc[mi][ni][r] + bb);
                *(uint2*)(Vt + (size_t)col * NROW + rowb) = pk.v;
            }
        }
    }
}

// ---------------- attention: R8 body + 4-buffer ring + FUSED 32KB V-phase ----------------
// Per kv-tile t: 4 K phases (16KB each) + ONE fused V phase (32KB, both V chunks
// already staged during K j=2,3). 5 barriers/t vs 6; the V stall windows merge into
// one WAITV0 whose loads had >=2 phases + softmax of flight time. Buffer rotation:
// chunk c of tile t lives in buf (2*(t&1)+c)&3 -- 2-tile cycle, all offsets cheap.
__device__ __forceinline__ void stageK(const ushort* __restrict__ Kh,
                                       const ushort* __restrict__ Kl,
                                       ushort* buf, int kv0, int kc0, int w, int lane) {
    size_t rowoff = (size_t)(kv0 + w * 16 + (lane & 15)) * EDIM + (lane >> 4) * 8 + kc0 * 32;
    GLD16(Kh + rowoff,      buf + w * 512);
    GLD16(Kh + rowoff + 32, buf + 2048 + w * 512);
    GLD16(Kl + rowoff,      buf + 4096 + w * 512);
    GLD16(Kl + rowoff + 32, buf + 6144 + w * 512);
}

__device__ __forceinline__ void stageV(const ushort* __restrict__ Vt,
                                       ushort* buf, int kv0, int vs0, int w, int lane) {
    size_t gv = (size_t)(vs0 * 64 + w * 16 + (lane & 15)) * NROW + kv0 + (lane >> 4) * 8;
    GLD16(Vt + gv,      buf + w * 1024);
    GLD16(Vt + gv + 32, buf + w * 1024 + 512);
    GLD16(Vt + gv + (size_t)64 * NROW,      buf + 4096 + w * 1024);
    GLD16(Vt + gv + (size_t)64 * NROW + 32, buf + 4096 + w * 1024 + 512);
}

__global__ __launch_bounds__(256, 2) void attn(
    const ushort* __restrict__ Qh, const ushort* __restrict__ Ql,
    const ushort* __restrict__ Kh, const ushort* __restrict__ Kl,
    const ushort* __restrict__ Vt, ushort* __restrict__ Op, float* __restrict__ mlbuf)
{
    __shared__ ushort KVbuf[4 * 8192];   // 64 KB: 4 rotating 16 KB chunk buffers
    __shared__ ushort Pall[4 * 1088];    // per-wave P slab (unit = ko*17+row)

    const int tid = threadIdx.x;
    const int lane = tid & 63;
    const int ln = tid & 15, quad = (tid >> 4) & 3, w = tid >> 6;
    ushort* Pw = Pall + w * 1088;

    const int id = blockIdx.x;              // 512 = qt(32) x [b(4) x kvq(4)]
    const int cls = id & 15;
    const int b = cls >> 2, kvq = cls & 3;
    const int qt = id >> 4;
    const int qrow0w = b * NT + qt * 64 + w * 16;
    const int kvbase = b * NT + kvq * 512;

    short8 qh8[8], ql8[8];
    #pragma unroll
    for (int kc = 0; kc < 8; ++kc) {
        qh8[kc] = *(const short8*)(Qh + (size_t)(qrow0w + ln) * EDIM + kc * 32 + quad * 8);
        ql8[kc] = *(const short8*)(Ql + (size_t)(qrow0w + ln) * EDIM + kc * 32 + quad * 8);
    }

    float m_r[4], l_r[4];
    #pragma unroll
    for (int r = 0; r < 4; ++r) { m_r[r] = -3e38f; l_r[r] = 0.f; }
    f32x4 o[16];
    #pragma unroll
    for (int ni = 0; ni < 16; ++ni) o[ni] = (f32x4){0.f, 0.f, 0.f, 0.f};

    // prologue: tile-0 K chunks 0,1 -> bufs 0,1
    stageK(Kh, Kl, KVbuf + 0 * 8192, kvbase, 0, w, lane);
    stageK(Kh, Kl, KVbuf + 1 * 8192, kvbase, 2, w, lane);

    #pragma unroll 1
    for (int t = 0; t < 8; ++t) {
        const int kv0 = kvbase + t * 64;
        const int pb = (t & 1) * 2;          // buffer rotation base (wave-uniform)
        f32x4 s[4];
        #pragma unroll
        for (int ni = 0; ni < 4; ++ni) s[ni] = (f32x4){0.f, 0.f, 0.f, 0.f};

        // ---- 4 K phases: chunk j in buf (pb+j)&3; stage K(j+2) / V(j-2) ahead ----
        #pragma unroll
        for (int j = 0; j < 4; ++j) {
            WAITV4();
            BAR();
            if (j < 2) stageK(Kh, Kl, KVbuf + ((pb + j + 2) & 3) * 8192, kv0, 2 * (j + 2), w, lane);
            else       stageV(Vt, KVbuf + ((pb + (j - 2)) & 3) * 8192, kv0, (j - 2) * 2, w, lane);

            const ushort* bufc = KVbuf + ((pb + j) & 3) * 8192;
            __builtin_amdgcn_s_setprio(1);
            #pragma unroll
            for (int kk = 0; kk < 2; ++kk) {
                const int kc = j * 2 + kk;
                #pragma unroll
                for (int ni = 0; ni < 4; ++ni) {
                    short8 bh = *(const short8*)(bufc + kk * 2048 + (ni * 64 + quad * 16 + ln) * 8);
                    short8 bl = *(const short8*)(bufc + 4096 + kk * 2048 + (ni * 64 + quad * 16 + ln) * 8);
                    s[ni] = MFMA16(qh8[kc], bh, s[ni]);
                    s[ni] = MFMA16(qh8[kc], bl, s[ni]);
                    s[ni] = MFMA16(ql8[kc], bh, s[ni]);
                }
            }
            __builtin_amdgcn_s_setprio(0);
        }

        // ---- online softmax with exact rescale-skip (V0,V1 in flight underneath) ----
        float mt[4];
        #pragma unroll
        for (int r = 0; r < 4; ++r)
            mt[r] = fmaxf(fmaxf(s[0][r], s[1][r]), fmaxf(s[2][r], s[3][r]));
        #pragma unroll
        for (int mask = 1; mask < 16; mask <<= 1)
            #pragma unroll
            for (int r = 0; r < 4; ++r)
                mt[r] = fmaxf(mt[r], __shfl_xor(mt[r], mask));
        int need = (mt[0] > m_r[0]) || (mt[1] > m_r[1]) ||
                   (mt[2] > m_r[2]) || (mt[3] > m_r[3]);
        if (__ballot(need)) {          // alpha == 1 exactly for every skipped lane-row
            float alpha[4];
            #pragma unroll
            for (int r = 0; r < 4; ++r) {
                float mn = fmaxf(m_r[r], mt[r]);
                alpha[r] = exp2f(m_r[r] - mn);
                m_r[r] = mn;
            }
            #pragma unroll
            for (int r = 0; r < 4; ++r) l_r[r] *= alpha[r];
            #pragma unroll
            for (int ni = 0; ni < 16; ++ni)
                #pragma unroll
                for (int r = 0; r < 4; ++r) o[ni][r] *= alpha[r];
        }
        float ls[4] = {0.f, 0.f, 0.f, 0.f};
        #pragma unroll
        for (int ni = 0; ni < 4; ++ni) {
            int colb = ni * 16 + ln;
            #pragma unroll
            for (int r = 0; r < 4; ++r) {
                float p = exp2f(s[ni][r] - m_r[r]);
                ls[r] += p;
                Pw[((colb >> 3) * 17 + quad * 4 + r) * 8 + (colb & 7)] = f2bf(p);
            }
        }
        #pragma unroll
        for (int mask = 1; mask < 16; mask <<= 1)
            #pragma unroll
            for (int r = 0; r < 4; ++r)
                ls[r] += __shfl_xor(ls[r], mask);
        #pragma unroll
        for (int r = 0; r < 4; ++r) l_r[r] += ls[r];

        short8 apk0 = *(const short8*)(Pw + (quad * 17 + ln) * 8);
        short8 apk1 = *(const short8*)(Pw + ((4 + quad) * 17 + ln) * 8);

        // ---- FUSED V phase: both 16KB V chunks (bufs pb, pb+1) in one barrier ----
        WAITV0();                        // V0: issued 2 phases+softmax ago; V1: 1 phase+softmax
        BAR();
        if (t < 7) {                     // stage next tile's K0,K1 under the fat V compute
            stageK(Kh, Kl, KVbuf + ((pb + 2) & 3) * 8192, kv0 + 64, 0, w, lane);
            stageK(Kh, Kl, KVbuf + ((pb + 3) & 3) * 8192, kv0 + 64, 2, w, lane);
        }
        __builtin_amdgcn_s_setprio(1);
        #pragma unroll
        for (int j2 = 0; j2 < 2; ++j2) {
            const ushort* bufc = KVbuf + ((pb + j2) & 3) * 8192;
            #pragma unroll
            for (int vv = 0; vv < 2; ++vv) {
                const int vs = j2 * 2 + vv;
                #pragma unroll
                for (int ni = 0; ni < 4; ++ni) {
                    short8 v0 = *(const short8*)(bufc + vv * 4096 + (ni * 128 + quad * 16 + ln) * 8);
                    short8 v1 = *(const short8*)(bufc + vv * 4096 + (ni * 128 + 64 + quad * 16 + ln) * 8);
                    o[vs * 4 + ni] = MFMA16(apk0, v0, o[vs * 4 + ni]);
                    o[vs * 4 + ni] = MFMA16(apk1, v1, o[vs * 4 + ni]);
                }
            }
        }
        __builtin_amdgcn_s_setprio(0);
    }

    // ---- epilogue: wave owns rows, write bf16 partial + (m,l) ----
    const int p = (b * 32 + qt) * 4 + kvq;
    if (ln == 0) {
        #pragma unroll
        for (int r = 0; r < 4; ++r) {
            int row = w * 16 + quad * 4 + r;
            *(float2*)(mlbuf + ((size_t)p * 64 + row) * 2) = make_float2(m_r[r], l_r[r]);
        }
    }
    #pragma unroll
    for (int ni = 0; ni < 16; ++ni)
        #pragma unroll
        for (int r = 0; r < 4; ++r) {
            int row = w * 16 + quad * 4 + r;
            Op[(size_t)p * 16384 + row * 256 + ni * 16 + ln] = f2bf(o[ni][r]);
        }
}

// ---------------- final merge of 4 kv-quarter partials ----------------
__global__ __launch_bounds__(256) void attn_merge(
    const ushort* __restrict__ Op, const float* __restrict__ mlbuf, float* __restrict__ out)
{
    const int bid = blockIdx.x, t = threadIdx.x;   // 512 blocks: b(4) x qt(32) x rg(4)
    const int b = bid >> 7, qt = (bid >> 2) & 31, rg = bid & 3;
    const int row = rg * 16 + (t >> 4);
    const int e0 = (t & 15) * 16;
    const int pb = (b * 32 + qt) * 4;
    float mv[4], lv[4];
    float M = -3e38f;
    #pragma unroll
    for (int w2 = 0; w2 < 4; ++w2) {
        float2 ml = *(const float2*)(mlbuf + ((size_t)(pb + w2) * 64 + row) * 2);
        mv[w2] = ml.x; lv[w2] = ml.y;
        M = fmaxf(M, ml.x);
    }
    float sc[4], denom = 0.f;
    #pragma unroll
    for (int w2 = 0; w2 < 4; ++w2) {
        sc[w2] = exp2f(mv[w2] - M);
        denom += sc[w2] * lv[w2];
    }
    float inv = 1.0f / denom;
    #pragma unroll
    for (int w2 = 0; w2 < 4; ++w2) sc[w2] *= inv;

    float acc[16] = {};
    #pragma unroll
    for (int w2 = 0; w2 < 4; ++w2) {
        const ushort* src = Op + (size_t)(pb + w2) * 16384 + row * 256 + e0;
        #pragma unroll
        for (int c = 0; c < 2; ++c) {
            union { ushort us[8]; uint4 v; } u;
            u.v = *(const uint4*)(src + c * 8);
            #pragma unroll
            for (int j = 0; j < 8; ++j)
                acc[c * 8 + j] += sc[w2] * bf2f(u.us[j]);
        }
    }
    float* op = out + ((size_t)b * NT + qt * 64 + row) * EDIM + e0;
    #pragma unroll
    for (int g = 0; g < 4; ++g)
        *(float4*)(op + g * 4) = make_float4(acc[g*4], acc[g*4+1], acc[g*4+2], acc[g*4+3]);
}

extern "C" void kernel_launch(void* const* d_in, const int* in_sizes, int n_in,
                              void* d_out, int out_size, void* d_ws, size_t ws_size,
                              hipStream_t stream) {
    const float* x  = (const float*)d_in[0];
    const float* Wq = (const float*)d_in[1];
    const float* bq = (const float*)d_in[2];
    const float* Wk = (const float*)d_in[3];
    const float* bk = (const float*)d_in[4];
    const float* Wv = (const float*)d_in[5];
    const float* bv = (const float*)d_in[6];
    float* out = (float*)d_out;

    const size_t NE = (size_t)NB * NT * EDIM;        // 2M elems
    ushort* Qh = (ushort*)d_ws;
    ushort* Ql = Qh + NE;
    ushort* Kh = Ql + NE;
    ushort* Kl = Kh + NE;
    ushort* Vt = Kl + NE;                            // [256][8192]
    ushort* Wqh = Vt + NE;
    ushort* Wql = Wqh + 256 * 1024;
    ushort* Wkh = Wql + 256 * 1024;
    ushort* Wkl = Wkh + 256 * 1024;
    ushort* Wvh = Wkl + 256 * 1024;
    ushort* Op  = Wvh + 256 * 1024;                  // 512 partials x 64 x 256 bf16 (16.8 MB)
    float*  mlb = (float*)(Op + (size_t)512 * 16384);// 512 x 64 x float2 (256 KB)
    // total ws ~= 39.6 MB

    split_w<<<384, 256, 0, stream>>>(Wq, Wk, Wv, Wqh, Wql, Wkh, Wkl, Wvh);
    qkv_proj<<<dim3(2, 128, 3), 256, 0, stream>>>(x, Wqh, Wql, Wkh, Wkl, Wvh,
                                                  bq, bk, bv, Qh, Ql, Kh, Kl, Vt);
    attn<<<512, 256, 0, stream>>>(Qh, Ql, Kh, Kl, Vt, Op, mlb);
    attn_merge<<<512, 256, 0, stream>>>(Op, mlb, out);
}